// Round 1
// baseline (111.244 us; speedup 1.0000x reference)
//
#include <hip/hip_runtime.h>

// Problem constants (B, N, M, K, Ci, C0, Co) from the reference setup.
constexpr int Bc = 4;
constexpr int Nc = 16384;
constexpr int Mc = 4096;
constexpr int Kc = 32;
constexpr int C0c = 64;
constexpr int COc = 128;
constexpr float EPSc = 1e-5f;

// ---------------------------------------------------------------------------
// Phase A: per-point encoders.  y_f = BN(feats @ W_feat), y_a = BN(feats @ W_attn)
// One lane per output channel; both 64-entry weight columns live in VGPRs.
// Block = 256 threads (4 waves), each block handles 64 points staged in LDS.
// ---------------------------------------------------------------------------
__global__ __launch_bounds__(256) void pt_phaseA(
    const float* __restrict__ feats,   // (npts, 64), already offset for batch chunk
    const float* __restrict__ Wf,      // (64, 64)
    const float* __restrict__ Wa,      // (64, 64)
    const float* __restrict__ fg, const float* __restrict__ fb,
    const float* __restrict__ fm, const float* __restrict__ fv,
    const float* __restrict__ ag, const float* __restrict__ ab,
    const float* __restrict__ am, const float* __restrict__ av,
    float* __restrict__ outf,          // (npts, 64)
    float* __restrict__ outa)          // (npts, 64)
{
    __shared__ float lf[64 * 64];
    const int tid = threadIdx.x;
    const int c = tid & 63;
    const int w = tid >> 6;
    const long long chunk = (long long)blockIdx.x * 64;

    // Weight columns -> registers (coalesced row reads, L1/L2-hot across blocks)
    float wf[64], wa[64];
#pragma unroll
    for (int i = 0; i < 64; ++i) {
        wf[i] = Wf[i * 64 + c];
        wa[i] = Wa[i * 64 + c];
    }
    const float fscale = fg[c] * rsqrtf(fv[c] + EPSc);
    const float fbias  = fb[c] - fm[c] * fscale;
    const float ascale = ag[c] * rsqrtf(av[c] + EPSc);
    const float abias  = ab[c] - am[c] * ascale;

    // Stage 64 points (64x64 fp32 = 16 KiB) into LDS, coalesced float4.
    const float4* src = (const float4*)(feats + chunk * 64);
    float4* dst = (float4*)lf;
#pragma unroll
    for (int i = 0; i < 4; ++i) dst[tid + 256 * i] = src[tid + 256 * i];
    __syncthreads();

    // Each wave handles 16 points; LDS reads are same-address broadcasts.
    for (int p = w * 16; p < w * 16 + 16; ++p) {
        float accf = 0.f, acca = 0.f;
        const float4* lfp = (const float4*)(lf + p * 64);
#pragma unroll
        for (int ii = 0; ii < 16; ++ii) {
            const float4 f4 = lfp[ii];
            accf = fmaf(f4.x, wf[ii * 4 + 0], accf);
            acca = fmaf(f4.x, wa[ii * 4 + 0], acca);
            accf = fmaf(f4.y, wf[ii * 4 + 1], accf);
            acca = fmaf(f4.y, wa[ii * 4 + 1], acca);
            accf = fmaf(f4.z, wf[ii * 4 + 2], accf);
            acca = fmaf(f4.z, wa[ii * 4 + 2], acca);
            accf = fmaf(f4.w, wf[ii * 4 + 3], accf);
            acca = fmaf(f4.w, wa[ii * 4 + 3], acca);
        }
        const long long o = (chunk + p) * 64 + c;
        outf[o] = accf * fscale + fbias;
        outa[o] = acca * ascale + abias;
    }
}

// ---------------------------------------------------------------------------
// Phase B: one wave per (b, m) group.
// Gather 32 neighbors, fuse xyz-proj+BN, per-lane softmax over K in registers,
// weighted sum, then 64->128 refine GEMM + BN + ReLU + empty-mask.
// ---------------------------------------------------------------------------
__global__ __launch_bounds__(64) void pt_phaseB(
    const float* __restrict__ xyz,    // (B, N, 3) global
    const float* __restrict__ nxyz,   // (B, M, 3) global
    const float* __restrict__ pf,     // (nb*N, 64) staged feat_feats (local batch idx)
    const float* __restrict__ pa,     // (nb*N, 64) staged attention
    const float* __restrict__ Wx,     // (3, 64)
    const float* __restrict__ xg, const float* __restrict__ xb,
    const float* __restrict__ xm, const float* __restrict__ xv,
    const float* __restrict__ Wr,     // (64, 128)
    const float* __restrict__ rg, const float* __restrict__ rb,
    const float* __restrict__ rm, const float* __restrict__ rv,
    const int* __restrict__ gidx,     // (B, M, 32) global
    const int* __restrict__ gcnt,     // (B, M) global
    float* __restrict__ out,          // (B, M, 128) global
    int b0)
{
    const int lane = threadIdx.x;          // 0..63 == channel
    const int lb = blockIdx.x >> 12;       // / Mc (4096)
    const int m = blockIdx.x & (Mc - 1);
    const int b = b0 + lb;
    const long long gbm = (long long)b * Mc + m;

    __shared__ int sidx[Kc];
    __shared__ float snf[C0c];

    if (lane < Kc) sidx[lane] = gidx[gbm * Kc + lane];
    const int cnt = gcnt[gbm];
    __syncthreads();

    if (cnt == 0) {   // uniform across the wave
        out[gbm * COc + lane] = 0.f;
        out[gbm * COc + 64 + lane] = 0.f;
        return;
    }

    const float nx0 = nxyz[gbm * 3 + 0];
    const float nx1 = nxyz[gbm * 3 + 1];
    const float nx2 = nxyz[gbm * 3 + 2];
    const float wx0 = Wx[lane];
    const float wx1 = Wx[64 + lane];
    const float wx2 = Wx[128 + lane];
    const float xscale = xg[lane] * rsqrtf(xv[lane] + EPSc);
    const float xbias  = xb[lane] - xm[lane] * xscale;

    float gf[Kc], ga[Kc];
#pragma unroll
    for (int k = 0; k < Kc; ++k) {
        const int n = sidx[k];
        const long long pbase = ((long long)lb * Nc + n) * 64;
        const float fval = pf[pbase + lane];      // coalesced 256B gather
        const float aval = pa[pbase + lane];
        const long long xo = ((long long)b * Nc + n) * 3;
        const float r0 = xyz[xo + 0] - nx0;       // wave-uniform broadcast loads
        const float r1 = xyz[xo + 1] - nx1;
        const float r2 = xyz[xo + 2] - nx2;
        const float gxf = (r0 * wx0 + r1 * wx1 + r2 * wx2) * xscale + xbias;
        gf[k] = fval + gxf;
        ga[k] = aval + gxf;
    }

    // Per-lane softmax over K (axis=2) — no cross-lane communication needed.
    float mx = gf[0];
#pragma unroll
    for (int k = 1; k < Kc; ++k) mx = fmaxf(mx, gf[k]);
    float s = 0.f, acc = 0.f;
#pragma unroll
    for (int k = 0; k < Kc; ++k) {
        const float e = __expf(gf[k] - mx);
        s += e;
        acc = fmaf(e, ga[k], acc);
    }
    snf[lane] = acc / s;
    __syncthreads();

    // Refine GEMM: 64 -> 128, W_ref rows read coalesced (L1-resident, 32 KiB).
    float a0 = 0.f, a1 = 0.f;
#pragma unroll
    for (int cc = 0; cc < C0c; ++cc) {
        const float nfv = snf[cc];                // LDS same-address broadcast
        a0 = fmaf(nfv, Wr[cc * COc + lane], a0);
        a1 = fmaf(nfv, Wr[cc * COc + 64 + lane], a1);
    }
    const float rs0 = rg[lane] * rsqrtf(rv[lane] + EPSc);
    const float rbi0 = rb[lane] - rm[lane] * rs0;
    const float rs1 = rg[64 + lane] * rsqrtf(rv[64 + lane] + EPSc);
    const float rbi1 = rb[64 + lane] - rm[64 + lane] * rs1;
    out[gbm * COc + lane]      = fmaxf(fmaf(a0, rs0, rbi0), 0.f);
    out[gbm * COc + 64 + lane] = fmaxf(fmaf(a1, rs1, rbi1), 0.f);
}

extern "C" void kernel_launch(void* const* d_in, const int* in_sizes, int n_in,
                              void* d_out, int out_size, void* d_ws, size_t ws_size,
                              hipStream_t stream)
{
    const float* xyz  = (const float*)d_in[0];
    const float* nxyz = (const float*)d_in[1];
    const float* feats = (const float*)d_in[2];
    const float* Wf = (const float*)d_in[3];
    const float* fg = (const float*)d_in[4];
    const float* fb = (const float*)d_in[5];
    const float* fm = (const float*)d_in[6];
    const float* fv = (const float*)d_in[7];
    const float* Wa = (const float*)d_in[8];
    const float* ag = (const float*)d_in[9];
    const float* ab = (const float*)d_in[10];
    const float* am = (const float*)d_in[11];
    const float* av = (const float*)d_in[12];
    const float* Wx = (const float*)d_in[13];
    const float* xg = (const float*)d_in[14];
    const float* xb = (const float*)d_in[15];
    const float* xm = (const float*)d_in[16];
    const float* xv = (const float*)d_in[17];
    const float* Wr = (const float*)d_in[18];
    const float* rg = (const float*)d_in[19];
    const float* rb = (const float*)d_in[20];
    const float* rm = (const float*)d_in[21];
    const float* rv = (const float*)d_in[22];
    const int* gidx = (const int*)d_in[23];
    const int* gcnt = (const int*)d_in[24];
    float* out = (float*)d_out;

    // Workspace: staged feat_feats + attention.  Full-batch needs 33.5 MB;
    // fall back to per-batch chunks (8.4 MB) if ws is small.
    const size_t per_b_floats = (size_t)Nc * C0c;
    const int nb = ((size_t)2 * Bc * per_b_floats * sizeof(float) <= ws_size) ? Bc : 1;

    for (int b0 = 0; b0 < Bc; b0 += nb) {
        float* pf = (float*)d_ws;
        float* pa = pf + (size_t)nb * per_b_floats;
        pt_phaseA<<<dim3((nb * Nc) / 64), dim3(256), 0, stream>>>(
            feats + (size_t)b0 * per_b_floats, Wf, Wa,
            fg, fb, fm, fv, ag, ab, am, av, pf, pa);
        pt_phaseB<<<dim3(nb * Mc), dim3(64), 0, stream>>>(
            xyz, nxyz, pf, pa, Wx, xg, xb, xm, xv,
            Wr, rg, rb, rm, rv, gidx, gcnt, out, b0);
    }
}

// Round 2
// 42.397 us; speedup vs baseline: 2.6239x; 2.6239x over previous
//
#include <hip/hip_runtime.h>

constexpr int Bc = 4, Nc = 16384, Mc = 4096, Kc = 32, C0c = 64, COc = 128;
constexpr float EPSc = 1e-5f;

using bf16x8 = __attribute__((ext_vector_type(8))) short;   // 8 bf16 (4 VGPRs)
using f32x4  = __attribute__((ext_vector_type(4))) float;   // 4 fp32

// round-to-nearest-even fp32 -> bf16 bits (inputs are normal floats here)
__device__ inline unsigned f2bf_bits(float x) {
    unsigned u = __float_as_uint(x);
    return (u + 0x7fffu + ((u >> 16) & 1u)) >> 16;
}
__device__ inline short f2bf(float x) { return (short)f2bf_bits(x); }

// ---------------------------------------------------------------------------
// Phase A (MFMA): Sfa[b*N+n][c] = pack( bf16(BN(feats@Wf)[c]), bf16(BN(feats@Wa)[c]) )
// One wave per 16-point tile, 8 col-tiles (cols 0-63 = feat, 64-127 = attn).
// BN scale folded into LDS-transposed bf16 weights; bias added at pack time.
// ---------------------------------------------------------------------------
__global__ __launch_bounds__(256) void pt_encode(
    const float* __restrict__ feats,
    const float* __restrict__ Wf, const float* __restrict__ Wa,
    const float* __restrict__ fg, const float* __restrict__ fb,
    const float* __restrict__ fm, const float* __restrict__ fv,
    const float* __restrict__ ag, const float* __restrict__ ab,
    const float* __restrict__ am, const float* __restrict__ av,
    unsigned* __restrict__ Sfa)
{
    __shared__ __align__(16) short WT[128][72];   // [col][k], pad 64->72 kills conflicts
    __shared__ float scl[128], bis[128];
    const int tid = threadIdx.x;
    if (tid < 128) {
        const int c = tid & 63;
        const float g  = (tid < 64) ? fg[c] : ag[c];
        const float v  = (tid < 64) ? fv[c] : av[c];
        const float bb = (tid < 64) ? fb[c] : ab[c];
        const float mm = (tid < 64) ? fm[c] : am[c];
        const float s = g * rsqrtf(v + EPSc);
        scl[tid] = s;
        bis[tid] = bb - mm * s;
    }
    __syncthreads();
#pragma unroll
    for (int i = 0; i < 16; ++i) {
        const int idx = tid + 256 * i;          // Wf/Wa element (k,c) = (idx>>6, idx&63)
        const int k = idx >> 6, c = idx & 63;
        WT[c][k]      = f2bf(Wf[idx] * scl[c]);
        WT[64 + c][k] = f2bf(Wa[idx] * scl[64 + c]);
    }
    __syncthreads();

    const int lane = tid & 63, w = tid >> 6;
    const int row16 = lane & 15, kg = lane >> 4;

    bf16x8 bfr[8][2];                            // B frags: lane holds W[kg*8+j][col]
#pragma unroll
    for (int t = 0; t < 8; ++t)
#pragma unroll
        for (int h = 0; h < 2; ++h)
            bfr[t][h] = *(const bf16x8*)&WT[16 * t + row16][32 * h + kg * 8];

    const long long pt = (long long)blockIdx.x * 4 + w;   // 4096 point-tiles
    const long long base = pt * 16;
    const float* arow = feats + (base + row16) * 64 + kg * 8;
    const float4 v0 = *(const float4*)(arow + 0);
    const float4 v1 = *(const float4*)(arow + 4);
    const float4 v2 = *(const float4*)(arow + 32);
    const float4 v3 = *(const float4*)(arow + 36);
    bf16x8 af0, af1;
    af0[0] = f2bf(v0.x); af0[1] = f2bf(v0.y); af0[2] = f2bf(v0.z); af0[3] = f2bf(v0.w);
    af0[4] = f2bf(v1.x); af0[5] = f2bf(v1.y); af0[6] = f2bf(v1.z); af0[7] = f2bf(v1.w);
    af1[0] = f2bf(v2.x); af1[1] = f2bf(v2.y); af1[2] = f2bf(v2.z); af1[3] = f2bf(v2.w);
    af1[4] = f2bf(v3.x); af1[5] = f2bf(v3.y); af1[6] = f2bf(v3.z); af1[7] = f2bf(v3.w);

    f32x4 acc[8];
#pragma unroll
    for (int t = 0; t < 8; ++t) {
        f32x4 z = {0.f, 0.f, 0.f, 0.f};
        z = __builtin_amdgcn_mfma_f32_16x16x32_bf16(af0, bfr[t][0], z, 0, 0, 0);
        z = __builtin_amdgcn_mfma_f32_16x16x32_bf16(af1, bfr[t][1], z, 0, 0, 0);
        acc[t] = z;
    }
    // C/D layout: row=(lane>>4)*4+reg, col=lane&15  [m89-verified]
#pragma unroll
    for (int t = 0; t < 4; ++t) {
        const int c = 16 * t + row16;
        const float bfv = bis[c], bav = bis[64 + c];
#pragma unroll
        for (int r = 0; r < 4; ++r) {
            const unsigned u = f2bf_bits(acc[t][r] + bfv)
                             | (f2bf_bits(acc[t + 4][r] + bav) << 16);
            Sfa[(base + kg * 4 + r) * 64 + c] = u;
        }
    }
}

// ---------------------------------------------------------------------------
// Phase B: one wave per group. Gather packed (f,a) dwords, fused xyz-proj with
// hoisted new_xyz part, branchless online softmax (no per-k register arrays).
// ---------------------------------------------------------------------------
__global__ __launch_bounds__(256) void pt_group(
    const float* __restrict__ xyz, const float* __restrict__ nxyz,
    const unsigned* __restrict__ Sfa,
    const float* __restrict__ Wx,
    const float* __restrict__ xg, const float* __restrict__ xb,
    const float* __restrict__ xm, const float* __restrict__ xv,
    const int* __restrict__ gidx,
    ushort* __restrict__ Snf)
{
    __shared__ int   sidx[4][32];
    __shared__ float sxyz[4][32][4];
    const int tid = threadIdx.x, lane = tid & 63, w = tid >> 6;
    const long long g = (long long)blockIdx.x * 4 + w;    // group = b*M + m
    const int b = (int)(g >> 12);

    if (lane < 32) {
        const int n = gidx[g * 32 + lane];
        sidx[w][lane] = n;
        const float* xp = xyz + ((long long)b * Nc + n) * 3;
        sxyz[w][lane][0] = xp[0];
        sxyz[w][lane][1] = xp[1];
        sxyz[w][lane][2] = xp[2];
    }
    __syncthreads();

    const float xs = xg[lane] * rsqrtf(xv[lane] + EPSc);
    const float w0 = Wx[lane] * xs, w1 = Wx[64 + lane] * xs, w2 = Wx[128 + lane] * xs;
    const float nx0 = nxyz[g * 3 + 0], nx1 = nxyz[g * 3 + 1], nx2 = nxyz[g * 3 + 2];
    const float Q = xb[lane] - xm[lane] * xs - (nx0 * w0 + nx1 * w1 + nx2 * w2);

    const unsigned* srow = Sfa + (long long)b * Nc * 64 + lane;
    float mx = -1e30f, ssum = 0.f, acc = 0.f;
#pragma unroll
    for (int k = 0; k < Kc; ++k) {
        const int n = sidx[w][k];
        const unsigned d = srow[n << 6];                  // 256B coalesced gather
        const float gxf = fmaf(sxyz[w][k][0], w0,
                          fmaf(sxyz[w][k][1], w1,
                          fmaf(sxyz[w][k][2], w2, Q)));
        const float f = __uint_as_float(d << 16) + gxf;
        const float a = __uint_as_float(d & 0xffff0000u) + gxf;
        const float nm = fmaxf(mx, f);
        const float r = __expf(mx - nm);
        const float e = __expf(f - nm);
        ssum = fmaf(ssum, r, e);
        acc  = fmaf(acc, r, e * a);
        mx = nm;
    }
    Snf[g * 64 + lane] = (ushort)f2bf_bits(acc / ssum);
}

// ---------------------------------------------------------------------------
// Phase C (MFMA): out = mask * relu(BN(Snf @ W_ref)), 16384x64 @ 64x128.
// Same structure as pt_encode; A operand is already bf16 (direct 16B loads).
// ---------------------------------------------------------------------------
__global__ __launch_bounds__(256) void pt_refine(
    const ushort* __restrict__ Snf,
    const float* __restrict__ Wr,
    const float* __restrict__ rg, const float* __restrict__ rb,
    const float* __restrict__ rm, const float* __restrict__ rv,
    const int* __restrict__ gcnt,
    float* __restrict__ out)
{
    __shared__ __align__(16) short WT[128][72];
    __shared__ float scl[128], bis[128];
    const int tid = threadIdx.x;
    if (tid < 128) {
        const float s = rg[tid] * rsqrtf(rv[tid] + EPSc);
        scl[tid] = s;
        bis[tid] = rb[tid] - rm[tid] * s;
    }
    __syncthreads();
#pragma unroll
    for (int i = 0; i < 32; ++i) {
        const int idx = tid + 256 * i;          // Wr element (k,c) = (idx>>7, idx&127)
        const int k = idx >> 7, c = idx & 127;
        WT[c][k] = f2bf(Wr[idx] * scl[c]);
    }
    __syncthreads();

    const int lane = tid & 63, w = tid >> 6;
    const int row16 = lane & 15, kg = lane >> 4;

    bf16x8 bfr[8][2];
#pragma unroll
    for (int t = 0; t < 8; ++t)
#pragma unroll
        for (int h = 0; h < 2; ++h)
            bfr[t][h] = *(const bf16x8*)&WT[16 * t + row16][32 * h + kg * 8];

    const long long pt = (long long)blockIdx.x * 4 + w;   // 1024 point-tiles
    const long long base = pt * 16;
    const ushort* arow = Snf + (base + row16) * 64 + kg * 8;
    const bf16x8 af0 = *(const bf16x8*)(arow);
    const bf16x8 af1 = *(const bf16x8*)(arow + 32);

    f32x4 acc[8];
#pragma unroll
    for (int t = 0; t < 8; ++t) {
        f32x4 z = {0.f, 0.f, 0.f, 0.f};
        z = __builtin_amdgcn_mfma_f32_16x16x32_bf16(af0, bfr[t][0], z, 0, 0, 0);
        z = __builtin_amdgcn_mfma_f32_16x16x32_bf16(af1, bfr[t][1], z, 0, 0, 0);
        acc[t] = z;
    }

    const int4 c4 = *(const int4*)(gcnt + base + kg * 4);
    const float msk[4] = { c4.x > 0 ? 1.f : 0.f, c4.y > 0 ? 1.f : 0.f,
                           c4.z > 0 ? 1.f : 0.f, c4.w > 0 ? 1.f : 0.f };
#pragma unroll
    for (int t = 0; t < 8; ++t) {
        const int c = 16 * t + row16;
        const float bb = bis[c];
#pragma unroll
        for (int r = 0; r < 4; ++r)
            out[(base + kg * 4 + r) * 128 + c] = fmaxf(acc[t][r] + bb, 0.f) * msk[r];
    }
}

extern "C" void kernel_launch(void* const* d_in, const int* in_sizes, int n_in,
                              void* d_out, int out_size, void* d_ws, size_t ws_size,
                              hipStream_t stream)
{
    const float* xyz  = (const float*)d_in[0];
    const float* nxyz = (const float*)d_in[1];
    const float* feats = (const float*)d_in[2];
    const float* Wf = (const float*)d_in[3];
    const float* fg = (const float*)d_in[4];
    const float* fb = (const float*)d_in[5];
    const float* fm = (const float*)d_in[6];
    const float* fv = (const float*)d_in[7];
    const float* Wa = (const float*)d_in[8];
    const float* ag = (const float*)d_in[9];
    const float* ab = (const float*)d_in[10];
    const float* am = (const float*)d_in[11];
    const float* av = (const float*)d_in[12];
    const float* Wx = (const float*)d_in[13];
    const float* xg = (const float*)d_in[14];
    const float* xb = (const float*)d_in[15];
    const float* xm = (const float*)d_in[16];
    const float* xv = (const float*)d_in[17];
    const float* Wr = (const float*)d_in[18];
    const float* rg = (const float*)d_in[19];
    const float* rb = (const float*)d_in[20];
    const float* rm = (const float*)d_in[21];
    const float* rv = (const float*)d_in[22];
    const int* gidx = (const int*)d_in[23];
    const int* gcnt = (const int*)d_in[24];
    float* out = (float*)d_out;

    // ws layout: Sfa (B*N*64 dwords = 16 MiB packed bf16 pairs) | Snf (B*M*64 bf16 = 2 MiB)
    unsigned* Sfa = (unsigned*)d_ws;
    ushort* Snf = (ushort*)((char*)d_ws + (size_t)Bc * Nc * 64 * sizeof(unsigned));

    pt_encode<<<dim3((Bc * Nc / 16) / 4), dim3(256), 0, stream>>>(
        feats, Wf, Wa, fg, fb, fm, fv, ag, ab, am, av, Sfa);
    pt_group<<<dim3((Bc * Mc) / 4), dim3(256), 0, stream>>>(
        xyz, nxyz, Sfa, Wx, xg, xb, xm, xv, gidx, Snf);
    pt_refine<<<dim3((Bc * Mc / 16) / 4), dim3(256), 0, stream>>>(
        Snf, Wr, rg, rb, rm, rv, gcnt, out);
}

// Round 3
// 38.655 us; speedup vs baseline: 2.8779x; 1.0968x over previous
//
#include <hip/hip_runtime.h>

constexpr int Bc = 4, Nc = 16384, Mc = 4096, Kc = 32;
constexpr float EPSc = 1e-5f;
constexpr float L2E = 1.4426950408889634f;   // log2(e)

using bf16x8 = __attribute__((ext_vector_type(8))) short;   // 8 bf16 (4 VGPRs)
using f32x4  = __attribute__((ext_vector_type(4))) float;   // 4 fp32

// round-to-nearest-even fp32 -> bf16 bits
__device__ inline unsigned f2bf_bits(float x) {
    unsigned u = __float_as_uint(x);
    return (u + 0x7fffu + ((u >> 16) & 1u)) >> 16;
}
__device__ inline short f2bf(float x) { return (short)f2bf_bits(x); }

// ---------------------------------------------------------------------------
// Phase A (MFMA): Sfa[b*N+n][c] = pack( hi=bf16(BN(feats@Wf)[c]*log2e),
//                                       lo=bf16(BN(feats@Wa)[c]) )
// Feat plane pre-scaled by log2e so phase B uses raw v_exp (exp2 domain).
// BN scale folded into LDS-transposed bf16 weights; bias added at pack time.
// ---------------------------------------------------------------------------
__global__ __launch_bounds__(256) void pt_encode(
    const float* __restrict__ feats,
    const float* __restrict__ Wf, const float* __restrict__ Wa,
    const float* __restrict__ fg, const float* __restrict__ fb,
    const float* __restrict__ fm, const float* __restrict__ fv,
    const float* __restrict__ ag, const float* __restrict__ ab,
    const float* __restrict__ am, const float* __restrict__ av,
    unsigned* __restrict__ Sfa)
{
    __shared__ __align__(16) short WT[128][72];   // [col][k], pad 64->72
    __shared__ float scl[128], bis[128];
    const int tid = threadIdx.x;
    if (tid < 128) {
        const int c = tid & 63;
        const float g  = (tid < 64) ? fg[c] : ag[c];
        const float v  = (tid < 64) ? fv[c] : av[c];
        const float bb = (tid < 64) ? fb[c] : ab[c];
        const float mm = (tid < 64) ? fm[c] : am[c];
        const float s = g * rsqrtf(v + EPSc);
        scl[tid] = (tid < 64) ? s * L2E : s;
        bis[tid] = (tid < 64) ? (bb - mm * s) * L2E : (bb - mm * s);
    }
    __syncthreads();
#pragma unroll
    for (int i = 0; i < 16; ++i) {
        const int idx = tid + 256 * i;          // (k,c) = (idx>>6, idx&63)
        const int k = idx >> 6, c = idx & 63;
        WT[c][k]      = f2bf(Wf[idx] * scl[c]);
        WT[64 + c][k] = f2bf(Wa[idx] * scl[64 + c]);
    }
    __syncthreads();

    const int lane = tid & 63, w = tid >> 6;
    const int row16 = lane & 15, kg = lane >> 4;

    bf16x8 bfr[8][2];                            // B frags: lane holds W[k][col]
#pragma unroll
    for (int t = 0; t < 8; ++t)
#pragma unroll
        for (int h = 0; h < 2; ++h)
            bfr[t][h] = *(const bf16x8*)&WT[16 * t + row16][32 * h + kg * 8];

    const long long pt = (long long)blockIdx.x * 4 + w;   // 4096 point-tiles
    const long long base = pt * 16;
    const float* arow = feats + (base + row16) * 64 + kg * 8;
    const float4 v0 = *(const float4*)(arow + 0);
    const float4 v1 = *(const float4*)(arow + 4);
    const float4 v2 = *(const float4*)(arow + 32);
    const float4 v3 = *(const float4*)(arow + 36);
    bf16x8 af0, af1;
    af0[0] = f2bf(v0.x); af0[1] = f2bf(v0.y); af0[2] = f2bf(v0.z); af0[3] = f2bf(v0.w);
    af0[4] = f2bf(v1.x); af0[5] = f2bf(v1.y); af0[6] = f2bf(v1.z); af0[7] = f2bf(v1.w);
    af1[0] = f2bf(v2.x); af1[1] = f2bf(v2.y); af1[2] = f2bf(v2.z); af1[3] = f2bf(v2.w);
    af1[4] = f2bf(v3.x); af1[5] = f2bf(v3.y); af1[6] = f2bf(v3.z); af1[7] = f2bf(v3.w);

    f32x4 acc[8];
#pragma unroll
    for (int t = 0; t < 8; ++t) {
        f32x4 z = {0.f, 0.f, 0.f, 0.f};
        z = __builtin_amdgcn_mfma_f32_16x16x32_bf16(af0, bfr[t][0], z, 0, 0, 0);
        z = __builtin_amdgcn_mfma_f32_16x16x32_bf16(af1, bfr[t][1], z, 0, 0, 0);
        acc[t] = z;
    }
    // C/D layout: row=(lane>>4)*4+reg, col=lane&15
#pragma unroll
    for (int t = 0; t < 4; ++t) {
        const int c = 16 * t + row16;
        const float bfv = bis[c], bav = bis[64 + c];
#pragma unroll
        for (int r = 0; r < 4; ++r) {
            const unsigned u = f2bf_bits(acc[t + 4][r] + bav)            // lo = attn
                             | (f2bf_bits(acc[t][r] + bfv) << 16);       // hi = feat*log2e
            Sfa[(base + kg * 4 + r) * 64 + c] = u;
        }
    }
}

// ---------------------------------------------------------------------------
// Phase B+C merged: 512 threads = 8 waves; 16 groups/block (2 per wave).
// Gather packed (f,a), exp2-domain softmax without max-sub, snf -> LDS,
// then the 64->128 refine MFMA (wave w = col-tile w) + BN + ReLU + mask.
// Block swizzle pins batch b to XCD pair {2b, 2b+1} (4.2 MB working set/XCD).
// ---------------------------------------------------------------------------
__global__ __launch_bounds__(512) void pt_gr(
    const float* __restrict__ xyz, const float* __restrict__ nxyz,
    const unsigned* __restrict__ Sfa,
    const float* __restrict__ Wx,
    const float* __restrict__ xg, const float* __restrict__ xb,
    const float* __restrict__ xm, const float* __restrict__ xv,
    const float* __restrict__ Wr,
    const float* __restrict__ rg, const float* __restrict__ rb,
    const float* __restrict__ rm, const float* __restrict__ rv,
    const int* __restrict__ gidx, const int* __restrict__ gcnt,
    float* __restrict__ out)
{
    __shared__ __align__(16) short WT[128][72];   // refine weights [col][k]
    __shared__ float scl_[128], bis[128];
    __shared__ __align__(16) short snf[16][72];   // softmax output tile [group][ch]
    __shared__ int   sidx[16][32];
    __shared__ float4 sxyz[16][32];

    const int tid = threadIdx.x, lane = tid & 63, w = tid >> 6;

    // bijective XCD-pinning swizzle: xcd = blk%8 handles batch (blk%8)>>1
    const int i = blockIdx.x;                     // 0..1023
    const int b = (i & 7) >> 1;
    const int j = ((i >> 3) << 1) | (i & 1);      // 0..255 tile within batch
    const long long gbase = (long long)b * Mc + j * 16;

    if (tid < 128) {
        const float s = rg[tid] * rsqrtf(rv[tid] + EPSc);
        scl_[tid] = s;
        bis[tid] = rb[tid] - rm[tid] * s;
    }
    {   // stage neighbor indices + xyz: one (group, k) per thread
        const int gi = tid >> 5, kk = tid & 31;
        const int n = gidx[(gbase + gi) * 32 + kk];
        sidx[gi][kk] = n;
        const float* xp = xyz + ((long long)b * Nc + n) * 3;
        sxyz[gi][kk] = make_float4(xp[0], xp[1], xp[2], 0.f);
    }
    __syncthreads();
#pragma unroll
    for (int it = 0; it < 16; ++it) {             // stage Wr * scale as bf16^T
        const int idx = tid + 512 * it;           // (k,c) = (idx>>7, idx&127)
        WT[idx & 127][idx >> 7] = f2bf(Wr[idx] * scl_[idx & 127]);
    }

    // per-lane channel coeffs (lane == channel)
    const float xs = xg[lane] * rsqrtf(xv[lane] + EPSc);
    const float w0 = Wx[lane] * xs, w1 = Wx[64 + lane] * xs, w2 = Wx[128 + lane] * xs;
    const float P = xb[lane] - xm[lane] * xs;

    const int gA = 2 * w, gB = 2 * w + 1;
    const float* nxA = nxyz + (gbase + gA) * 3;
    const float* nxB = nxyz + (gbase + gB) * 3;
    const float QA = P - fmaf(nxA[0], w0, fmaf(nxA[1], w1, nxA[2] * w2));
    const float QB = P - fmaf(nxB[0], w0, fmaf(nxB[1], w1, nxB[2] * w2));

    const unsigned* srow = Sfa + (long long)b * (Nc * 64) + lane;
    float ssA = 0.f, acA = 0.f, ssB = 0.f, acB = 0.f;
#pragma unroll 4
    for (int k = 0; k < Kc; ++k) {
        const unsigned dA = srow[sidx[gA][k] << 6];   // 256B coalesced gathers
        const unsigned dB = srow[sidx[gB][k] << 6];
        const float4 xA = sxyz[gA][k];                // LDS broadcast
        const float4 xB = sxyz[gB][k];
        const float gxA = fmaf(xA.x, w0, fmaf(xA.y, w1, fmaf(xA.z, w2, QA)));
        const float gxB = fmaf(xB.x, w0, fmaf(xB.y, w1, fmaf(xB.z, w2, QB)));
        // hi16 = f*log2e (bf16), lo16 = a (bf16); no max-sub needed (|f|<<88)
        const float eA = __builtin_amdgcn_exp2f(fmaf(gxA, L2E, __uint_as_float(dA & 0xffff0000u)));
        const float eB = __builtin_amdgcn_exp2f(fmaf(gxB, L2E, __uint_as_float(dB & 0xffff0000u)));
        const float aA = __uint_as_float(dA << 16) + gxA;
        const float aB = __uint_as_float(dB << 16) + gxB;
        ssA += eA; acA = fmaf(eA, aA, acA);
        ssB += eB; acB = fmaf(eB, aB, acB);
    }
    snf[gA][lane] = f2bf(acA / ssA);
    snf[gB][lane] = f2bf(acB / ssB);
    __syncthreads();

    // refine MFMA: A = snf tile (rows=groups), B = WT col-tile w
    const int row16 = lane & 15, kg = lane >> 4;
    const bf16x8 af0 = *(const bf16x8*)&snf[row16][kg * 8];
    const bf16x8 af1 = *(const bf16x8*)&snf[row16][32 + kg * 8];
    const bf16x8 bf0 = *(const bf16x8*)&WT[16 * w + row16][kg * 8];
    const bf16x8 bf1 = *(const bf16x8*)&WT[16 * w + row16][32 + kg * 8];
    f32x4 z = {0.f, 0.f, 0.f, 0.f};
    z = __builtin_amdgcn_mfma_f32_16x16x32_bf16(af0, bf0, z, 0, 0, 0);
    z = __builtin_amdgcn_mfma_f32_16x16x32_bf16(af1, bf1, z, 0, 0, 0);

    const int4 c4 = *(const int4*)(gcnt + gbase + kg * 4);
    const int cc = 16 * w + row16;
    const float bb = bis[cc];
    float* orow = out + (gbase + kg * 4) * 128 + cc;
    orow[0]   = fmaxf(z[0] + bb, 0.f) * (c4.x > 0 ? 1.f : 0.f);
    orow[128] = fmaxf(z[1] + bb, 0.f) * (c4.y > 0 ? 1.f : 0.f);
    orow[256] = fmaxf(z[2] + bb, 0.f) * (c4.z > 0 ? 1.f : 0.f);
    orow[384] = fmaxf(z[3] + bb, 0.f) * (c4.w > 0 ? 1.f : 0.f);
}

extern "C" void kernel_launch(void* const* d_in, const int* in_sizes, int n_in,
                              void* d_out, int out_size, void* d_ws, size_t ws_size,
                              hipStream_t stream)
{
    const float* xyz  = (const float*)d_in[0];
    const float* nxyz = (const float*)d_in[1];
    const float* feats = (const float*)d_in[2];
    const float* Wf = (const float*)d_in[3];
    const float* fg = (const float*)d_in[4];
    const float* fb = (const float*)d_in[5];
    const float* fm = (const float*)d_in[6];
    const float* fv = (const float*)d_in[7];
    const float* Wa = (const float*)d_in[8];
    const float* ag = (const float*)d_in[9];
    const float* ab = (const float*)d_in[10];
    const float* am = (const float*)d_in[11];
    const float* av = (const float*)d_in[12];
    const float* Wx = (const float*)d_in[13];
    const float* xg = (const float*)d_in[14];
    const float* xb = (const float*)d_in[15];
    const float* xm = (const float*)d_in[16];
    const float* xv = (const float*)d_in[17];
    const float* Wr = (const float*)d_in[18];
    const float* rg = (const float*)d_in[19];
    const float* rb = (const float*)d_in[20];
    const float* rm = (const float*)d_in[21];
    const float* rv = (const float*)d_in[22];
    const int* gidx = (const int*)d_in[23];
    const int* gcnt = (const int*)d_in[24];
    float* out = (float*)d_out;

    unsigned* Sfa = (unsigned*)d_ws;   // B*N*64 dwords = 16 MiB packed bf16 pairs

    pt_encode<<<dim3((Bc * Nc / 16) / 4), dim3(256), 0, stream>>>(
        feats, Wf, Wa, fg, fb, fm, fv, ag, ab, am, av, Sfa);
    pt_gr<<<dim3((Bc * Mc) / 16), dim3(512), 0, stream>>>(
        xyz, nxyz, Sfa, Wx, xg, xb, xm, xv,
        Wr, rg, rb, rm, rv, gidx, gcnt, out);
}